// Round 22
// baseline (55.388 us; speedup 1.0000x reference)
//
#include <hip/hip_runtime.h>
#include <stdint.h>

// JointGNNEncoder fused 2-layer GCN, MI355X (gfx950).
// out[b] = mean_n ReLU( A @ ( ReLU( A @ (X W1) + b1 ) W2 ) + b2 )
// A@(X W) = (A@X) W ; A is tridiagonal (chains are index-contiguous).
// R22 = R17 + producer-consumer GEMM1->GEMM2 handoff:
//   ldsH chunk c (f-cols c*64..c*64+63, all 48 rows) is produced ENTIRELY by
//   wave c -> barrC replaced by per-chunk release/acquire LDS flags. Each
//   wave starts GEMM2 on its OWN chunk (no sync; same-wave RAW) and consumes
//   chunks in order (ow+j)&3. ONE barrier total (barrA). Accumulation order
//   permutes per wave (f32; margin 4.4x - fine). Flags: 16B LDS, no deadlock
//   (every wave sets before spinning), no added cross-phase registers.

typedef __attribute__((ext_vector_type(8))) __bf16 bf16x8;
typedef __attribute__((ext_vector_type(4))) __bf16 bf16x4;
typedef __attribute__((ext_vector_type(4))) float f32x4;

// XOR bits 4..6 by row&7: spreads 16B slots of same-bank rows across banks
#define SWZ(row, byteoff) ((unsigned)(byteoff) ^ ((((unsigned)(row)) & 7u) << 4))

// ---------------------------------------------------------------------------
// prep: pack bf16 weights in per-fragment lane order.
// GEMM1 frag block idx = (hf*2 + ks): lane l holds
//   W1T(h = hf*16 + (l&15), k = ks*32 + (l>>4)*8 + j), j=0..7  -> ws[0,32K)
// GEMM2 frag block idx = ((of*4 + c)*2 + ks): lane l holds
//   W2T(o = of*16 + (l&15), f = c*64 + ks*32 + (l>>4)*8 + j)   -> ws[32K,160K)
// ---------------------------------------------------------------------------
__global__ void prep_kernel(const float* __restrict__ W1,
                            const float* __restrict__ W2,
                            unsigned char* __restrict__ ws) {
  int t = blockIdx.x * blockDim.x + threadIdx.x;
  bf16x8 v;
  if (t < 2048) {                     // GEMM1: 32 blocks * 64 lanes
    int blk = t >> 6, l = t & 63;
    int ks = blk & 1, hf = blk >> 1;
    int h  = hf * 16 + (l & 15);
    int k0 = ks * 32 + (l >> 4) * 8;
#pragma unroll
    for (int j = 0; j < 8; ++j) v[j] = (__bf16)W1[(k0 + j) * 256 + h];
    *(bf16x8*)(ws + t * 16) = v;
  } else if (t < 10240) {             // GEMM2: 128 blocks * 64 lanes
    int t2 = t - 2048;
    int blk = t2 >> 6, l = t2 & 63;
    int ks = blk & 1;
    int c  = (blk >> 1) & 3;
    int of = blk >> 3;
    int o  = of * 16 + (l & 15);
    int f0 = c * 64 + ks * 32 + (l >> 4) * 8;
#pragma unroll
    for (int j = 0; j < 8; ++j) v[j] = (__bf16)W2[(f0 + j) * 256 + o];
    *(bf16x8*)(ws + 32768 + t2 * 16) = v;
  }
}

// ---------------------------------------------------------------------------
// main fused kernel: 256 threads = 4 waves; block = 2 graphs = 48 rows.
// wave ow = wid: o-tile ow*64 (4 fi); each wave covers all 48 rows (3 fj).
// ---------------------------------------------------------------------------
__launch_bounds__(256, 4)
__global__ void gnn_kernel(const float* __restrict__ X,
                           const float* __restrict__ b1g,
                           const float* __restrict__ b2g,
                           const float* __restrict__ Ag,
                           const unsigned char* __restrict__ ws,
                           float* __restrict__ out) {
  __shared__ __align__(16) unsigned char ldsX[48 * 128];   // X' bf16 swz 6K
  __shared__ __align__(16) unsigned char ldsH[48 * 512];   // H1 bf16 swz 24K
  __shared__ __align__(16) float ldsB1[256];
  __shared__ __align__(16) float ldsB2[256];
  __shared__ __align__(16) float wdT[24];   // A[n][n-1], 0 at n=0
  __shared__ __align__(16) float w0T[24];   // A[n][n]
  __shared__ __align__(16) float wuT[24];   // A[n][n+1], 0 at n=23
  __shared__ int ldsFlag[4];                // H1-chunk ready flags

  const int tid  = threadIdx.x;
  const int lane = tid & 63;
  const int ow   = tid >> 6;           // wave id = o-tile = produced H-chunk
  const int g0   = blockIdx.x * 2;
  const long row0 = (long)g0 * 24;

  ldsB1[tid] = b1g[tid];
  ldsB2[tid] = b2g[tid];
  if (tid < 24) {
    wdT[tid] = tid > 0  ? Ag[tid * 25 - 1] : 0.f;
    w0T[tid] = Ag[tid * 25];
    wuT[tid] = tid < 23 ? Ag[tid * 25 + 1] : 0.f;
  }
  if (tid < 4) ldsFlag[tid] = 0;       // visible after barrA

  const int r16   = lane & 15;
  const int kgrp  = (lane >> 4) * 8;
  const int lbyte = lane * 16;

  // ---- X' = (A @ X) rows (tridiagonal mix) -> bf16 swizzled into ldsX
#pragma unroll
  for (int it = 0; it < 3; ++it) {
    int idx = tid + it * 256;            // 48 rows x 16 float4-chunks
    int m   = idx >> 4;
    int c4  = (idx & 15) * 4;
    int n   = m - (m / 24) * 24;
    int md  = (n > 0)  ? m - 1 : m;      // clamped; weight 0 at chain start
    int mu  = (n < 23) ? m + 1 : m;      // clamped; weight 0 at chain end
    int od  = (n > 0)  ? n * 25 - 1 : 0;
    int ou  = (n < 23) ? n * 25 + 1 : 0;
    float wmid = Ag[n * 25];
    float wdn  = Ag[od];  wdn = (n > 0)  ? wdn : 0.f;
    float wup  = Ag[ou];  wup = (n < 23) ? wup : 0.f;
    float4 xc = *(const float4*)(X + (row0 + m)  * 64 + c4);
    float4 xd = *(const float4*)(X + (row0 + md) * 64 + c4);
    float4 xu = *(const float4*)(X + (row0 + mu) * 64 + c4);
    float ax = wmid * xc.x + wdn * xd.x + wup * xu.x;
    float ay = wmid * xc.y + wdn * xd.y + wup * xu.y;
    float az = wmid * xc.z + wdn * xd.z + wup * xu.z;
    float aw = wmid * xc.w + wdn * xd.w + wup * xu.w;
    bf16x4 p;
    p[0] = (__bf16)ax; p[1] = (__bf16)ay; p[2] = (__bf16)az; p[3] = (__bf16)aw;
    *(bf16x4*)(ldsX + SWZ(m, m * 128 + c4 * 2)) = p;
  }
  __syncthreads();   // barrA: X' + biases + tables + flag init ready (ONLY barrier)

  f32x4 acc[4][3];
  const f32x4 z4 = {0.f, 0.f, 0.f, 0.f};
#pragma unroll
  for (int i = 0; i < 4; ++i)
#pragma unroll
    for (int j = 0; j < 3; ++j) acc[i][j] = z4;

  // ---- GEMM1: D[h][m] = W1T(h,k) * X'(m,k)^T, K=64
#pragma unroll
  for (int ks = 0; ks < 2; ++ks) {
    bf16x8 af[4], bf[3];
    int koff = (ks * 32 + kgrp) * 2;
#pragma unroll
    for (int fi = 0; fi < 4; ++fi)
      af[fi] = *(const bf16x8*)(ws + ((((ow * 4 + fi) * 2) + ks) << 10) + lbyte);
#pragma unroll
    for (int fj = 0; fj < 3; ++fj) {
      int m = fj * 16 + r16;
      bf[fj] = *(const bf16x8*)(ldsX + SWZ(m, m * 128 + koff));
    }
#pragma unroll
    for (int fi = 0; fi < 4; ++fi)
#pragma unroll
      for (int fj = 0; fj < 3; ++fj)
        acc[fi][fj] = __builtin_amdgcn_mfma_f32_16x16x32_bf16(af[fi], bf[fj], acc[fi][fj], 0, 0, 0);
  }

  // ---- epilogue1: bias + ReLU -> H1[m][h] bf16; this wave produces the
  // complete chunk ow (h-cols ow*64..ow*64+63, all 48 rows).
  {
    int hr = (lane >> 4) * 4;
#pragma unroll
    for (int fi = 0; fi < 4; ++fi) {
      int h = ow * 64 + fi * 16 + hr;
      float4 bb = *(const float4*)&ldsB1[h];
#pragma unroll
      for (int fj = 0; fj < 3; ++fj) {
        int m = fj * 16 + r16;
        f32x4 v = acc[fi][fj];
        bf16x4 p;
        p[0] = (__bf16)fmaxf(v[0] + bb.x, 0.f);
        p[1] = (__bf16)fmaxf(v[1] + bb.y, 0.f);
        p[2] = (__bf16)fmaxf(v[2] + bb.z, 0.f);
        p[3] = (__bf16)fmaxf(v[3] + bb.w, 0.f);
        *(bf16x4*)(ldsH + SWZ(m, m * 512 + h * 2)) = p;
      }
    }
  }
  // publish chunk ow (release: drains ds_writes before the flag store)
  __hip_atomic_store(&ldsFlag[ow], 1, __ATOMIC_RELEASE, __HIP_MEMORY_SCOPE_WORKGROUP);

  // ---- GEMM2 (operands swapped): D[m][o] = H1(m,f) * W2T(o,f)^T, K=256.
  // Chunk order (ow+j)&3: own chunk first (no wait), others flag-gated.
  f32x4 acc2[3][4];
#pragma unroll
  for (int j = 0; j < 3; ++j)
#pragma unroll
    for (int i = 0; i < 4; ++i) acc2[j][i] = z4;

  const unsigned char* w2p = ws + 32768;
  bf16x8 afc[4];
#pragma unroll
  for (int fi = 0; fi < 4; ++fi)    // step 0: chunk (ow+0)&3 = ow, ks=0
    afc[fi] = *(const bf16x8*)(w2p + ((((ow * 4 + fi) * 4 + ow) * 2 + 0) << 10) + lbyte);

#pragma unroll
  for (int s = 0; s < 8; ++s) {
    const int j  = s >> 1;
    const int ks = s & 1;
    const int c  = (ow + j) & 3;
    bf16x8 afn[4];
    if (s < 7) {
      const int j2  = (s + 1) >> 1;
      const int ks2 = (s + 1) & 1;
      const int c2  = (ow + j2) & 3;
#pragma unroll
      for (int fi = 0; fi < 4; ++fi)
        afn[fi] = *(const bf16x8*)(w2p + ((((ow * 4 + fi) * 4 + c2) * 2 + ks2) << 10) + lbyte);
    }
    if (ks == 0 && j > 0) {   // first use of a foreign chunk: acquire-gate
      while (__hip_atomic_load(&ldsFlag[c], __ATOMIC_ACQUIRE,
                               __HIP_MEMORY_SCOPE_WORKGROUP) == 0) { }
    }
    bf16x8 bf[3];
    int foff = (c * 64 + ks * 32 + kgrp) * 2;
#pragma unroll
    for (int fj = 0; fj < 3; ++fj) {
      int m = fj * 16 + r16;
      bf[fj] = *(const bf16x8*)(ldsH + SWZ(m, m * 512 + foff));
    }
#pragma unroll
    for (int fj = 0; fj < 3; ++fj)
#pragma unroll
      for (int fi = 0; fi < 4; ++fi)
        acc2[fj][fi] = __builtin_amdgcn_mfma_f32_16x16x32_bf16(bf[fj], afc[fi], acc2[fj][fi], 0, 0, 0);
#pragma unroll
    for (int fi = 0; fi < 4; ++fi) afc[fi] = afn[fi];
  }
  // no barrier needed: everything below is in-register

  // ---- final: in-register tri-mix + bias + ReLU + mean-pool over 24 nodes.
  // acc2[fj][fi][r] = Z[m][o], m lm = fj*16 + grp*4 + r (grp = lane>>4),
  // graph = (lm >= 24), n = lm % 24. Edge weights wdT[0] = wuT[23] = 0 kill
  // cross-graph garbage automatically.
  {
    const int grp = lane >> 4;
    const int l16 = lane & 15;
    const int src_up = (lane - 16) & 63;   // receive value of lane-16
    const int src_dn = (lane + 16) & 63;   // receive value of lane+16

    // batch ALL cross-lane moves first: 24 DS ops, latencies overlap
    float s3[4][3], s0[4][3];
#pragma unroll
    for (int fi = 0; fi < 4; ++fi)
#pragma unroll
      for (int fj = 0; fj < 3; ++fj) {
        s3[fi][fj] = __shfl(acc2[fj][fi][3], src_up);  // Z[lm-1] cand for r=0
        s0[fi][fj] = __shfl(acc2[fj][fi][0], src_dn);  // Z[lm+1] cand for r=3
      }

#pragma unroll
    for (int fi = 0; fi < 4; ++fi) {
      const int o = ow * 64 + fi * 16 + l16;
      const float b2v = ldsB2[o];
      float p0 = 0.f, p1 = 0.f;
#pragma unroll
      for (int fj = 0; fj < 3; ++fj) {
        const int lmb = fj * 16 + grp * 4;
        const int nb  = (lmb < 24) ? lmb : lmb - 24;
        f32x4 wd4 = *(const f32x4*)&wdT[nb];
        f32x4 w04 = *(const f32x4*)&w0T[nb];
        f32x4 wu4 = *(const f32x4*)&wuT[nb];
        f32x4 v = acc2[fj][fi];
        float zl0 = s3[fi][fj], zr3 = s0[fi][fj];
        if (fj > 0 && grp == 0) zl0 = s3[fi][fj - 1];  // cross-frag left nbr
        if (fj < 2 && grp == 3) zr3 = s0[fi][fj + 1];  // cross-frag right nbr
        float q0 = b2v + wd4[0] * zl0 + w04[0] * v[0] + wu4[0] * v[1];
        float q1 = b2v + wd4[1] * v[0] + w04[1] * v[1] + wu4[1] * v[2];
        float q2 = b2v + wd4[2] * v[1] + w04[2] * v[2] + wu4[2] * v[3];
        float q3 = b2v + wd4[3] * v[2] + w04[3] * v[3] + wu4[3] * zr3;
        float qs = fmaxf(q0, 0.f) + fmaxf(q1, 0.f) +
                   fmaxf(q2, 0.f) + fmaxf(q3, 0.f);
        if (fj == 0) p0 += qs;
        else if (fj == 2) p1 += qs;
        else { bool low = grp < 2; p0 += low ? qs : 0.f; p1 += low ? 0.f : qs; }
      }
      // pool across the 4 row-groups (same l16 = same o)
      p0 += __shfl_xor(p0, 16); p0 += __shfl_xor(p0, 32);
      p1 += __shfl_xor(p1, 16); p1 += __shfl_xor(p1, 32);
      if (grp == 0) out[(size_t)(g0)     * 256 + o] = p0 * (1.f / 24.f);
      if (grp == 1) out[(size_t)(g0 + 1) * 256 + o] = p1 * (1.f / 24.f);
    }
  }
}

extern "C" void kernel_launch(void* const* d_in, const int* in_sizes, int n_in,
                              void* d_out, int out_size, void* d_ws, size_t ws_size,
                              hipStream_t stream) {
  (void)n_in; (void)out_size; (void)ws_size;
  const float* X  = (const float*)d_in[0];
  const float* W1 = (const float*)d_in[1];
  const float* b1 = (const float*)d_in[2];
  const float* W2 = (const float*)d_in[3];
  const float* b2 = (const float*)d_in[4];
  const float* A  = (const float*)d_in[5];
  float* out = (float*)d_out;
  unsigned char* ws = (unsigned char*)d_ws;

  int B = in_sizes[0] / (24 * 64);   // 8192
  prep_kernel<<<40, 256, 0, stream>>>(W1, W2, ws);
  gnn_kernel<<<B / 2, 256, 0, stream>>>(X, b1, b2, A, ws, out);
}

// Round 23
// 55.059 us; speedup vs baseline: 1.0060x; 1.0060x over previous
//
#include <hip/hip_runtime.h>
#include <stdint.h>

// JointGNNEncoder fused 2-layer GCN, MI355X (gfx950).  FINAL (session best).
// out[b] = mean_n ReLU( A @ ( ReLU( A @ (X W1) + b1 ) W2 ) + b2 )
// A@(X W) = (A@X) W ; A is tridiagonal (chains are index-contiguous).
// Structure (R17, 54.9us = 586 TF, absmax 1.95e-3):
//   prep: W1^T/W2^T -> bf16, packed in per-MFMA-fragment lane order in ws.
//   main: 256 thr / 4 waves / 2 graphs (48 rows). Phases:
//     stage (coalesced tridiag X-mix -> swizzled ldsX) -> barrier ->
//     GEMM1 (16x16x32 bf16, weights direct from L2) -> bias+ReLU -> ldsH
//     -> barrier -> GEMM2 (operands swapped: D[m][o], 1-step weight
//     prefetch) -> in-register tri-mix + bias + ReLU + mean-pool (shuffles).
// Constraints measured this session (R5/R9-R10/R14/R16/R18/R20/R22):
//   - cross-GEMM register live-ranges spill to scratch (3 events)
//   - occupancy beyond ~8 waves/CU does not pay (shared-latency lockstep)
//   - removing/softening barriers (flags, zero-barrier) is worth ~0
//   - in-register X-mix from global is uncoalesced (16x transactions)
// Plateau = per-wave dependent phase-chain latency; not a HW roofline.

typedef __attribute__((ext_vector_type(8))) __bf16 bf16x8;
typedef __attribute__((ext_vector_type(4))) __bf16 bf16x4;
typedef __attribute__((ext_vector_type(4))) float f32x4;

// XOR bits 4..6 by row&7: spreads 16B slots of same-bank rows across banks
#define SWZ(row, byteoff) ((unsigned)(byteoff) ^ ((((unsigned)(row)) & 7u) << 4))

// ---------------------------------------------------------------------------
// prep: pack bf16 weights in per-fragment lane order.
// GEMM1 frag block idx = (hf*2 + ks): lane l holds
//   W1T(h = hf*16 + (l&15), k = ks*32 + (l>>4)*8 + j), j=0..7  -> ws[0,32K)
// GEMM2 frag block idx = ((of*4 + c)*2 + ks): lane l holds
//   W2T(o = of*16 + (l&15), f = c*64 + ks*32 + (l>>4)*8 + j)   -> ws[32K,160K)
// ---------------------------------------------------------------------------
__global__ void prep_kernel(const float* __restrict__ W1,
                            const float* __restrict__ W2,
                            unsigned char* __restrict__ ws) {
  int t = blockIdx.x * blockDim.x + threadIdx.x;
  bf16x8 v;
  if (t < 2048) {                     // GEMM1: 32 blocks * 64 lanes
    int blk = t >> 6, l = t & 63;
    int ks = blk & 1, hf = blk >> 1;
    int h  = hf * 16 + (l & 15);
    int k0 = ks * 32 + (l >> 4) * 8;
#pragma unroll
    for (int j = 0; j < 8; ++j) v[j] = (__bf16)W1[(k0 + j) * 256 + h];
    *(bf16x8*)(ws + t * 16) = v;
  } else if (t < 10240) {             // GEMM2: 128 blocks * 64 lanes
    int t2 = t - 2048;
    int blk = t2 >> 6, l = t2 & 63;
    int ks = blk & 1;
    int c  = (blk >> 1) & 3;
    int of = blk >> 3;
    int o  = of * 16 + (l & 15);
    int f0 = c * 64 + ks * 32 + (l >> 4) * 8;
#pragma unroll
    for (int j = 0; j < 8; ++j) v[j] = (__bf16)W2[(f0 + j) * 256 + o];
    *(bf16x8*)(ws + 32768 + t2 * 16) = v;
  }
}

// ---------------------------------------------------------------------------
// main fused kernel: 256 threads = 4 waves; block = 2 graphs = 48 rows.
// wave ow = wid: o-tile ow*64 (4 fi); each wave covers all 48 rows (3 fj).
// ldsX and ldsH are separate regions -> no union-protect barrier needed.
// ---------------------------------------------------------------------------
__launch_bounds__(256, 4)
__global__ void gnn_kernel(const float* __restrict__ X,
                           const float* __restrict__ b1g,
                           const float* __restrict__ b2g,
                           const float* __restrict__ Ag,
                           const unsigned char* __restrict__ ws,
                           float* __restrict__ out) {
  __shared__ __align__(16) unsigned char ldsX[48 * 128];   // X' bf16 swz 6K
  __shared__ __align__(16) unsigned char ldsH[48 * 512];   // H1 bf16 swz 24K
  __shared__ __align__(16) float ldsB1[256];
  __shared__ __align__(16) float ldsB2[256];
  __shared__ __align__(16) float wdT[24];   // A[n][n-1], 0 at n=0
  __shared__ __align__(16) float w0T[24];   // A[n][n]
  __shared__ __align__(16) float wuT[24];   // A[n][n+1], 0 at n=23

  const int tid  = threadIdx.x;
  const int lane = tid & 63;
  const int ow   = tid >> 6;           // wave id = o-tile
  const int g0   = blockIdx.x * 2;
  const long row0 = (long)g0 * 24;

  ldsB1[tid] = b1g[tid];
  ldsB2[tid] = b2g[tid];
  if (tid < 24) {
    wdT[tid] = tid > 0  ? Ag[tid * 25 - 1] : 0.f;
    w0T[tid] = Ag[tid * 25];
    wuT[tid] = tid < 23 ? Ag[tid * 25 + 1] : 0.f;
  }

  const int r16   = lane & 15;
  const int kgrp  = (lane >> 4) * 8;
  const int lbyte = lane * 16;

  // ---- X' = (A @ X) rows (tridiagonal mix) -> bf16 swizzled into ldsX
  // Unconditional clamped loads: no divergent branches, loads batchable.
#pragma unroll
  for (int it = 0; it < 3; ++it) {
    int idx = tid + it * 256;            // 48 rows x 16 float4-chunks
    int m   = idx >> 4;
    int c4  = (idx & 15) * 4;
    int n   = m - (m / 24) * 24;
    int md  = (n > 0)  ? m - 1 : m;      // clamped; weight 0 at chain start
    int mu  = (n < 23) ? m + 1 : m;      // clamped; weight 0 at chain end
    int od  = (n > 0)  ? n * 25 - 1 : 0;
    int ou  = (n < 23) ? n * 25 + 1 : 0;
    float wmid = Ag[n * 25];
    float wdn  = Ag[od];  wdn = (n > 0)  ? wdn : 0.f;
    float wup  = Ag[ou];  wup = (n < 23) ? wup : 0.f;
    float4 xc = *(const float4*)(X + (row0 + m)  * 64 + c4);
    float4 xd = *(const float4*)(X + (row0 + md) * 64 + c4);
    float4 xu = *(const float4*)(X + (row0 + mu) * 64 + c4);
    float ax = wmid * xc.x + wdn * xd.x + wup * xu.x;
    float ay = wmid * xc.y + wdn * xd.y + wup * xu.y;
    float az = wmid * xc.z + wdn * xd.z + wup * xu.z;
    float aw = wmid * xc.w + wdn * xd.w + wup * xu.w;
    bf16x4 p;
    p[0] = (__bf16)ax; p[1] = (__bf16)ay; p[2] = (__bf16)az; p[3] = (__bf16)aw;
    *(bf16x4*)(ldsX + SWZ(m, m * 128 + c4 * 2)) = p;
  }
  __syncthreads();   // barrA: X' + biases + coeff tables ready

  f32x4 acc[4][3];
  const f32x4 z4 = {0.f, 0.f, 0.f, 0.f};
#pragma unroll
  for (int i = 0; i < 4; ++i)
#pragma unroll
    for (int j = 0; j < 3; ++j) acc[i][j] = z4;

  // ---- GEMM1: D[h][m] = W1T(h,k) * X'(m,k)^T, K=64
#pragma unroll
  for (int ks = 0; ks < 2; ++ks) {
    bf16x8 af[4], bf[3];
    int koff = (ks * 32 + kgrp) * 2;
#pragma unroll
    for (int fi = 0; fi < 4; ++fi)
      af[fi] = *(const bf16x8*)(ws + ((((ow * 4 + fi) * 2) + ks) << 10) + lbyte);
#pragma unroll
    for (int fj = 0; fj < 3; ++fj) {
      int m = fj * 16 + r16;
      bf[fj] = *(const bf16x8*)(ldsX + SWZ(m, m * 128 + koff));
    }
#pragma unroll
    for (int fi = 0; fi < 4; ++fi)
#pragma unroll
      for (int fj = 0; fj < 3; ++fj)
        acc[fi][fj] = __builtin_amdgcn_mfma_f32_16x16x32_bf16(af[fi], bf[fj], acc[fi][fj], 0, 0, 0);
  }
  // no barrier here: ldsX and ldsH are separate regions

  // ---- epilogue1: bias + ReLU -> H1[m][h] bf16 (D: col=lane&15=m, row=(lane>>4)*4+reg=h)
  {
    int hr = (lane >> 4) * 4;
#pragma unroll
    for (int fi = 0; fi < 4; ++fi) {
      int h = ow * 64 + fi * 16 + hr;
      float4 bb = *(const float4*)&ldsB1[h];
#pragma unroll
      for (int fj = 0; fj < 3; ++fj) {
        int m = fj * 16 + r16;
        f32x4 v = acc[fi][fj];
        bf16x4 p;
        p[0] = (__bf16)fmaxf(v[0] + bb.x, 0.f);
        p[1] = (__bf16)fmaxf(v[1] + bb.y, 0.f);
        p[2] = (__bf16)fmaxf(v[2] + bb.z, 0.f);
        p[3] = (__bf16)fmaxf(v[3] + bb.w, 0.f);
        *(bf16x4*)(ldsH + SWZ(m, m * 512 + h * 2)) = p;
      }
    }
  }
  __syncthreads();   // barrC: H1 ready

  // ---- GEMM2 (operands swapped): D[m][o] = H1(m,f) * W2T(o,f)^T, K=256
  // lane holds m = fj*16 + (lane>>4)*4 + r (4 consecutive rows),
  // o = ow*64 + fi*16 + (lane&15).
  f32x4 acc2[3][4];
#pragma unroll
  for (int j = 0; j < 3; ++j)
#pragma unroll
    for (int i = 0; i < 4; ++i) acc2[j][i] = z4;

  const unsigned char* w2p = ws + 32768;
  bf16x8 afc[4];
#pragma unroll
  for (int fi = 0; fi < 4; ++fi)    // step 0 (c=0, ks=0)
    afc[fi] = *(const bf16x8*)(w2p + ((((ow * 4 + fi) * 4 + 0) * 2 + 0) << 10) + lbyte);

#pragma unroll
  for (int s = 0; s < 8; ++s) {
    const int c  = s >> 1;
    const int ks = s & 1;
    bf16x8 afn[4];
    if (s < 7) {
      const int c2  = (s + 1) >> 1;
      const int ks2 = (s + 1) & 1;
#pragma unroll
      for (int fi = 0; fi < 4; ++fi)
        afn[fi] = *(const bf16x8*)(w2p + ((((ow * 4 + fi) * 4 + c2) * 2 + ks2) << 10) + lbyte);
    }
    bf16x8 bf[3];
    int foff = (c * 64 + ks * 32 + kgrp) * 2;
#pragma unroll
    for (int fj = 0; fj < 3; ++fj) {
      int m = fj * 16 + r16;
      bf[fj] = *(const bf16x8*)(ldsH + SWZ(m, m * 512 + foff));
    }
#pragma unroll
    for (int fj = 0; fj < 3; ++fj)
#pragma unroll
      for (int fi = 0; fi < 4; ++fi)
        acc2[fj][fi] = __builtin_amdgcn_mfma_f32_16x16x32_bf16(bf[fj], afc[fi], acc2[fj][fi], 0, 0, 0);
#pragma unroll
    for (int fi = 0; fi < 4; ++fi) afc[fi] = afn[fi];
  }
  // no barrier needed: everything below is in-register

  // ---- final: in-register tri-mix + bias + ReLU + mean-pool over 24 nodes.
  // acc2[fj][fi][r] = Z[m][o], m lm = fj*16 + grp*4 + r (grp = lane>>4),
  // graph = (lm >= 24), n = lm % 24. Edge weights wdT[0] = wuT[23] = 0 kill
  // cross-graph garbage automatically.
  {
    const int grp = lane >> 4;
    const int l16 = lane & 15;
    const int src_up = (lane - 16) & 63;   // receive value of lane-16
    const int src_dn = (lane + 16) & 63;   // receive value of lane+16

    // batch ALL cross-lane moves first: 24 DS ops, latencies overlap
    float s3[4][3], s0[4][3];
#pragma unroll
    for (int fi = 0; fi < 4; ++fi)
#pragma unroll
      for (int fj = 0; fj < 3; ++fj) {
        s3[fi][fj] = __shfl(acc2[fj][fi][3], src_up);  // Z[lm-1] cand for r=0
        s0[fi][fj] = __shfl(acc2[fj][fi][0], src_dn);  // Z[lm+1] cand for r=3
      }

#pragma unroll
    for (int fi = 0; fi < 4; ++fi) {
      const int o = ow * 64 + fi * 16 + l16;
      const float b2v = ldsB2[o];
      float p0 = 0.f, p1 = 0.f;
#pragma unroll
      for (int fj = 0; fj < 3; ++fj) {
        const int lmb = fj * 16 + grp * 4;
        const int nb  = (lmb < 24) ? lmb : lmb - 24;
        f32x4 wd4 = *(const f32x4*)&wdT[nb];
        f32x4 w04 = *(const f32x4*)&w0T[nb];
        f32x4 wu4 = *(const f32x4*)&wuT[nb];
        f32x4 v = acc2[fj][fi];
        float zl0 = s3[fi][fj], zr3 = s0[fi][fj];
        if (fj > 0 && grp == 0) zl0 = s3[fi][fj - 1];  // cross-frag left nbr
        if (fj < 2 && grp == 3) zr3 = s0[fi][fj + 1];  // cross-frag right nbr
        float q0 = b2v + wd4[0] * zl0 + w04[0] * v[0] + wu4[0] * v[1];
        float q1 = b2v + wd4[1] * v[0] + w04[1] * v[1] + wu4[1] * v[2];
        float q2 = b2v + wd4[2] * v[1] + w04[2] * v[2] + wu4[2] * v[3];
        float q3 = b2v + wd4[3] * v[2] + w04[3] * v[3] + wu4[3] * zr3;
        float qs = fmaxf(q0, 0.f) + fmaxf(q1, 0.f) +
                   fmaxf(q2, 0.f) + fmaxf(q3, 0.f);
        if (fj == 0) p0 += qs;
        else if (fj == 2) p1 += qs;
        else { bool low = grp < 2; p0 += low ? qs : 0.f; p1 += low ? 0.f : qs; }
      }
      // pool across the 4 row-groups (same l16 = same o)
      p0 += __shfl_xor(p0, 16); p0 += __shfl_xor(p0, 32);
      p1 += __shfl_xor(p1, 16); p1 += __shfl_xor(p1, 32);
      if (grp == 0) out[(size_t)(g0)     * 256 + o] = p0 * (1.f / 24.f);
      if (grp == 1) out[(size_t)(g0 + 1) * 256 + o] = p1 * (1.f / 24.f);
    }
  }
}

extern "C" void kernel_launch(void* const* d_in, const int* in_sizes, int n_in,
                              void* d_out, int out_size, void* d_ws, size_t ws_size,
                              hipStream_t stream) {
  (void)n_in; (void)out_size; (void)ws_size;
  const float* X  = (const float*)d_in[0];
  const float* W1 = (const float*)d_in[1];
  const float* b1 = (const float*)d_in[2];
  const float* W2 = (const float*)d_in[3];
  const float* b2 = (const float*)d_in[4];
  const float* A  = (const float*)d_in[5];
  float* out = (float*)d_out;
  unsigned char* ws = (unsigned char*)d_ws;

  int B = in_sizes[0] / (24 * 64);   // 8192
  prep_kernel<<<40, 256, 0, stream>>>(W1, W2, ws);
  gnn_kernel<<<B / 2, 256, 0, stream>>>(X, b1, b2, A, ws, out);
}

// Round 24
// 53.778 us; speedup vs baseline: 1.0299x; 1.0238x over previous
//
#include <hip/hip_runtime.h>
#include <stdint.h>

// JointGNNEncoder fused 2-layer GCN, MI355X (gfx950).
// out[b] = mean_n ReLU( A @ ( ReLU( A @ (X W1) + b1 ) W2 ) + b2 )
// A@(X W) = (A@X) W ; A is tridiagonal (chains are index-contiguous).
// R24 = R17 + 2-step-deep rotating weight prefetch in GEMM2 (3 live 4-frag
// sets afA/afB/afC, +16 VGPR): cover 180->360cy >= warm-L2 latency. Unlike
// R16 (full preload at kernel entry: entry serialization, occupancy drop)
// the loads are issued inside GEMM2 and carry no cross-phase live range.

typedef __attribute__((ext_vector_type(8))) __bf16 bf16x8;
typedef __attribute__((ext_vector_type(4))) __bf16 bf16x4;
typedef __attribute__((ext_vector_type(4))) float f32x4;

// XOR bits 4..6 by row&7: spreads 16B slots of same-bank rows across banks
#define SWZ(row, byteoff) ((unsigned)(byteoff) ^ ((((unsigned)(row)) & 7u) << 4))

// ---------------------------------------------------------------------------
// prep: pack bf16 weights in per-fragment lane order.
// GEMM1 frag block idx = (hf*2 + ks): lane l holds
//   W1T(h = hf*16 + (l&15), k = ks*32 + (l>>4)*8 + j), j=0..7  -> ws[0,32K)
// GEMM2 frag block idx = ((of*4 + c)*2 + ks): lane l holds
//   W2T(o = of*16 + (l&15), f = c*64 + ks*32 + (l>>4)*8 + j)   -> ws[32K,160K)
// ---------------------------------------------------------------------------
__global__ void prep_kernel(const float* __restrict__ W1,
                            const float* __restrict__ W2,
                            unsigned char* __restrict__ ws) {
  int t = blockIdx.x * blockDim.x + threadIdx.x;
  bf16x8 v;
  if (t < 2048) {                     // GEMM1: 32 blocks * 64 lanes
    int blk = t >> 6, l = t & 63;
    int ks = blk & 1, hf = blk >> 1;
    int h  = hf * 16 + (l & 15);
    int k0 = ks * 32 + (l >> 4) * 8;
#pragma unroll
    for (int j = 0; j < 8; ++j) v[j] = (__bf16)W1[(k0 + j) * 256 + h];
    *(bf16x8*)(ws + t * 16) = v;
  } else if (t < 10240) {             // GEMM2: 128 blocks * 64 lanes
    int t2 = t - 2048;
    int blk = t2 >> 6, l = t2 & 63;
    int ks = blk & 1;
    int c  = (blk >> 1) & 3;
    int of = blk >> 3;
    int o  = of * 16 + (l & 15);
    int f0 = c * 64 + ks * 32 + (l >> 4) * 8;
#pragma unroll
    for (int j = 0; j < 8; ++j) v[j] = (__bf16)W2[(f0 + j) * 256 + o];
    *(bf16x8*)(ws + 32768 + t2 * 16) = v;
  }
}

// ---------------------------------------------------------------------------
// main fused kernel: 256 threads = 4 waves; block = 2 graphs = 48 rows.
// wave ow = wid: o-tile ow*64 (4 fi); each wave covers all 48 rows (3 fj).
// ldsX and ldsH are separate regions -> no union-protect barrier needed.
// ---------------------------------------------------------------------------
__launch_bounds__(256, 4)
__global__ void gnn_kernel(const float* __restrict__ X,
                           const float* __restrict__ b1g,
                           const float* __restrict__ b2g,
                           const float* __restrict__ Ag,
                           const unsigned char* __restrict__ ws,
                           float* __restrict__ out) {
  __shared__ __align__(16) unsigned char ldsX[48 * 128];   // X' bf16 swz 6K
  __shared__ __align__(16) unsigned char ldsH[48 * 512];   // H1 bf16 swz 24K
  __shared__ __align__(16) float ldsB1[256];
  __shared__ __align__(16) float ldsB2[256];
  __shared__ __align__(16) float wdT[24];   // A[n][n-1], 0 at n=0
  __shared__ __align__(16) float w0T[24];   // A[n][n]
  __shared__ __align__(16) float wuT[24];   // A[n][n+1], 0 at n=23

  const int tid  = threadIdx.x;
  const int lane = tid & 63;
  const int ow   = tid >> 6;           // wave id = o-tile
  const int g0   = blockIdx.x * 2;
  const long row0 = (long)g0 * 24;

  ldsB1[tid] = b1g[tid];
  ldsB2[tid] = b2g[tid];
  if (tid < 24) {
    wdT[tid] = tid > 0  ? Ag[tid * 25 - 1] : 0.f;
    w0T[tid] = Ag[tid * 25];
    wuT[tid] = tid < 23 ? Ag[tid * 25 + 1] : 0.f;
  }

  const int r16   = lane & 15;
  const int kgrp  = (lane >> 4) * 8;
  const int lbyte = lane * 16;

  // ---- X' = (A @ X) rows (tridiagonal mix) -> bf16 swizzled into ldsX
  // Unconditional clamped loads: no divergent branches, loads batchable.
#pragma unroll
  for (int it = 0; it < 3; ++it) {
    int idx = tid + it * 256;            // 48 rows x 16 float4-chunks
    int m   = idx >> 4;
    int c4  = (idx & 15) * 4;
    int n   = m - (m / 24) * 24;
    int md  = (n > 0)  ? m - 1 : m;      // clamped; weight 0 at chain start
    int mu  = (n < 23) ? m + 1 : m;      // clamped; weight 0 at chain end
    int od  = (n > 0)  ? n * 25 - 1 : 0;
    int ou  = (n < 23) ? n * 25 + 1 : 0;
    float wmid = Ag[n * 25];
    float wdn  = Ag[od];  wdn = (n > 0)  ? wdn : 0.f;
    float wup  = Ag[ou];  wup = (n < 23) ? wup : 0.f;
    float4 xc = *(const float4*)(X + (row0 + m)  * 64 + c4);
    float4 xd = *(const float4*)(X + (row0 + md) * 64 + c4);
    float4 xu = *(const float4*)(X + (row0 + mu) * 64 + c4);
    float ax = wmid * xc.x + wdn * xd.x + wup * xu.x;
    float ay = wmid * xc.y + wdn * xd.y + wup * xu.y;
    float az = wmid * xc.z + wdn * xd.z + wup * xu.z;
    float aw = wmid * xc.w + wdn * xd.w + wup * xu.w;
    bf16x4 p;
    p[0] = (__bf16)ax; p[1] = (__bf16)ay; p[2] = (__bf16)az; p[3] = (__bf16)aw;
    *(bf16x4*)(ldsX + SWZ(m, m * 128 + c4 * 2)) = p;
  }
  __syncthreads();   // barrA: X' + biases + coeff tables ready

  f32x4 acc[4][3];
  const f32x4 z4 = {0.f, 0.f, 0.f, 0.f};
#pragma unroll
  for (int i = 0; i < 4; ++i)
#pragma unroll
    for (int j = 0; j < 3; ++j) acc[i][j] = z4;

  // ---- GEMM1: D[h][m] = W1T(h,k) * X'(m,k)^T, K=64
#pragma unroll
  for (int ks = 0; ks < 2; ++ks) {
    bf16x8 af[4], bf[3];
    int koff = (ks * 32 + kgrp) * 2;
#pragma unroll
    for (int fi = 0; fi < 4; ++fi)
      af[fi] = *(const bf16x8*)(ws + ((((ow * 4 + fi) * 2) + ks) << 10) + lbyte);
#pragma unroll
    for (int fj = 0; fj < 3; ++fj) {
      int m = fj * 16 + r16;
      bf[fj] = *(const bf16x8*)(ldsX + SWZ(m, m * 128 + koff));
    }
#pragma unroll
    for (int fi = 0; fi < 4; ++fi)
#pragma unroll
      for (int fj = 0; fj < 3; ++fj)
        acc[fi][fj] = __builtin_amdgcn_mfma_f32_16x16x32_bf16(af[fi], bf[fj], acc[fi][fj], 0, 0, 0);
  }
  // no barrier here: ldsX and ldsH are separate regions

  // ---- epilogue1: bias + ReLU -> H1[m][h] bf16 (D: col=lane&15=m, row=(lane>>4)*4+reg=h)
  {
    int hr = (lane >> 4) * 4;
#pragma unroll
    for (int fi = 0; fi < 4; ++fi) {
      int h = ow * 64 + fi * 16 + hr;
      float4 bb = *(const float4*)&ldsB1[h];
#pragma unroll
      for (int fj = 0; fj < 3; ++fj) {
        int m = fj * 16 + r16;
        f32x4 v = acc[fi][fj];
        bf16x4 p;
        p[0] = (__bf16)fmaxf(v[0] + bb.x, 0.f);
        p[1] = (__bf16)fmaxf(v[1] + bb.y, 0.f);
        p[2] = (__bf16)fmaxf(v[2] + bb.z, 0.f);
        p[3] = (__bf16)fmaxf(v[3] + bb.w, 0.f);
        *(bf16x4*)(ldsH + SWZ(m, m * 512 + h * 2)) = p;
      }
    }
  }
  __syncthreads();   // barrC: H1 ready

  // ---- GEMM2 (operands swapped): D[m][o] = H1(m,f) * W2T(o,f)^T, K=256.
  // 2-step-deep rotating prefetch: afA = step s, afB = s+1, afC <- s+2.
  // lane holds m = fj*16 + (lane>>4)*4 + r (4 consecutive rows),
  // o = ow*64 + fi*16 + (lane&15).
  f32x4 acc2[3][4];
#pragma unroll
  for (int j = 0; j < 3; ++j)
#pragma unroll
    for (int i = 0; i < 4; ++i) acc2[j][i] = z4;

  const unsigned char* w2p = ws + 32768;
#define W2ADDR(s, fi) ((const bf16x8*)(w2p + \
    ((((ow * 4 + (fi)) * 4 + ((s) >> 1)) * 2 + ((s) & 1)) << 10) + lbyte))

  bf16x8 afA[4], afB[4];
#pragma unroll
  for (int fi = 0; fi < 4; ++fi) afA[fi] = *W2ADDR(0, fi);
#pragma unroll
  for (int fi = 0; fi < 4; ++fi) afB[fi] = *W2ADDR(1, fi);

#pragma unroll
  for (int s = 0; s < 8; ++s) {
    bf16x8 afC[4];
    if (s < 6) {
#pragma unroll
      for (int fi = 0; fi < 4; ++fi) afC[fi] = *W2ADDR(s + 2, fi);
    }
    const int c  = s >> 1;
    const int ks = s & 1;
    bf16x8 bf[3];
    int foff = (c * 64 + ks * 32 + kgrp) * 2;
#pragma unroll
    for (int fj = 0; fj < 3; ++fj) {
      int m = fj * 16 + r16;
      bf[fj] = *(const bf16x8*)(ldsH + SWZ(m, m * 512 + foff));
    }
#pragma unroll
    for (int fj = 0; fj < 3; ++fj)
#pragma unroll
      for (int fi = 0; fi < 4; ++fi)
        acc2[fj][fi] = __builtin_amdgcn_mfma_f32_16x16x32_bf16(bf[fj], afA[fi], acc2[fj][fi], 0, 0, 0);
#pragma unroll
    for (int fi = 0; fi < 4; ++fi) { afA[fi] = afB[fi]; afB[fi] = afC[fi]; }
  }
#undef W2ADDR
  // no barrier needed: everything below is in-register

  // ---- final: in-register tri-mix + bias + ReLU + mean-pool over 24 nodes.
  // acc2[fj][fi][r] = Z[m][o], m lm = fj*16 + grp*4 + r (grp = lane>>4),
  // graph = (lm >= 24), n = lm % 24. Edge weights wdT[0] = wuT[23] = 0 kill
  // cross-graph garbage automatically.
  {
    const int grp = lane >> 4;
    const int l16 = lane & 15;
    const int src_up = (lane - 16) & 63;   // receive value of lane-16
    const int src_dn = (lane + 16) & 63;   // receive value of lane+16

    // batch ALL cross-lane moves first: 24 DS ops, latencies overlap
    float s3[4][3], s0[4][3];
#pragma unroll
    for (int fi = 0; fi < 4; ++fi)
#pragma unroll
      for (int fj = 0; fj < 3; ++fj) {
        s3[fi][fj] = __shfl(acc2[fj][fi][3], src_up);  // Z[lm-1] cand for r=0
        s0[fi][fj] = __shfl(acc2[fj][fi][0], src_dn);  // Z[lm+1] cand for r=3
      }

#pragma unroll
    for (int fi = 0; fi < 4; ++fi) {
      const int o = ow * 64 + fi * 16 + l16;
      const float b2v = ldsB2[o];
      float p0 = 0.f, p1 = 0.f;
#pragma unroll
      for (int fj = 0; fj < 3; ++fj) {
        const int lmb = fj * 16 + grp * 4;
        const int nb  = (lmb < 24) ? lmb : lmb - 24;
        f32x4 wd4 = *(const f32x4*)&wdT[nb];
        f32x4 w04 = *(const f32x4*)&w0T[nb];
        f32x4 wu4 = *(const f32x4*)&wuT[nb];
        f32x4 v = acc2[fj][fi];
        float zl0 = s3[fi][fj], zr3 = s0[fi][fj];
        if (fj > 0 && grp == 0) zl0 = s3[fi][fj - 1];  // cross-frag left nbr
        if (fj < 2 && grp == 3) zr3 = s0[fi][fj + 1];  // cross-frag right nbr
        float q0 = b2v + wd4[0] * zl0 + w04[0] * v[0] + wu4[0] * v[1];
        float q1 = b2v + wd4[1] * v[0] + w04[1] * v[1] + wu4[1] * v[2];
        float q2 = b2v + wd4[2] * v[1] + w04[2] * v[2] + wu4[2] * v[3];
        float q3 = b2v + wd4[3] * v[2] + w04[3] * v[3] + wu4[3] * zr3;
        float qs = fmaxf(q0, 0.f) + fmaxf(q1, 0.f) +
                   fmaxf(q2, 0.f) + fmaxf(q3, 0.f);
        if (fj == 0) p0 += qs;
        else if (fj == 2) p1 += qs;
        else { bool low = grp < 2; p0 += low ? qs : 0.f; p1 += low ? 0.f : qs; }
      }
      // pool across the 4 row-groups (same l16 = same o)
      p0 += __shfl_xor(p0, 16); p0 += __shfl_xor(p0, 32);
      p1 += __shfl_xor(p1, 16); p1 += __shfl_xor(p1, 32);
      if (grp == 0) out[(size_t)(g0)     * 256 + o] = p0 * (1.f / 24.f);
      if (grp == 1) out[(size_t)(g0 + 1) * 256 + o] = p1 * (1.f / 24.f);
    }
  }
}

extern "C" void kernel_launch(void* const* d_in, const int* in_sizes, int n_in,
                              void* d_out, int out_size, void* d_ws, size_t ws_size,
                              hipStream_t stream) {
  (void)n_in; (void)out_size; (void)ws_size;
  const float* X  = (const float*)d_in[0];
  const float* W1 = (const float*)d_in[1];
  const float* b1 = (const float*)d_in[2];
  const float* W2 = (const float*)d_in[3];
  const float* b2 = (const float*)d_in[4];
  const float* A  = (const float*)d_in[5];
  float* out = (float*)d_out;
  unsigned char* ws = (unsigned char*)d_ws;

  int B = in_sizes[0] / (24 * 64);   // 8192
  prep_kernel<<<40, 256, 0, stream>>>(W1, W2, ws);
  gnn_kernel<<<B / 2, 256, 0, stream>>>(X, b1, b2, A, ws, out);
}

// Round 25
// 53.627 us; speedup vs baseline: 1.0328x; 1.0028x over previous
//
#include <hip/hip_runtime.h>
#include <stdint.h>

// JointGNNEncoder fused 2-layer GCN, MI355X (gfx950).
// out[b] = mean_n ReLU( A @ ( ReLU( A @ (X W1) + b1 ) W2 ) + b2 )
// A@(X W) = (A@X) W ; A is tridiagonal (chains are index-contiguous).
// R25 = R24 (53.8us: 2-step rotating W2 prefetch) + GEMM1 weight fragments
// (af1[2][4], 32 VGPR) issued BEFORE the X-staging loop: their L2 latency
// hides under the ~2us stage phase, GEMM1's head becomes pure LDS+MFMA.
// (R5-R7-proven pattern; unlike R16 no entry serialization - only 8 loads.)

typedef __attribute__((ext_vector_type(8))) __bf16 bf16x8;
typedef __attribute__((ext_vector_type(4))) __bf16 bf16x4;
typedef __attribute__((ext_vector_type(4))) float f32x4;

// XOR bits 4..6 by row&7: spreads 16B slots of same-bank rows across banks
#define SWZ(row, byteoff) ((unsigned)(byteoff) ^ ((((unsigned)(row)) & 7u) << 4))

// ---------------------------------------------------------------------------
// prep: pack bf16 weights in per-fragment lane order.
// GEMM1 frag block idx = (hf*2 + ks): lane l holds
//   W1T(h = hf*16 + (l&15), k = ks*32 + (l>>4)*8 + j), j=0..7  -> ws[0,32K)
// GEMM2 frag block idx = ((of*4 + c)*2 + ks): lane l holds
//   W2T(o = of*16 + (l&15), f = c*64 + ks*32 + (l>>4)*8 + j)   -> ws[32K,160K)
// ---------------------------------------------------------------------------
__global__ void prep_kernel(const float* __restrict__ W1,
                            const float* __restrict__ W2,
                            unsigned char* __restrict__ ws) {
  int t = blockIdx.x * blockDim.x + threadIdx.x;
  bf16x8 v;
  if (t < 2048) {                     // GEMM1: 32 blocks * 64 lanes
    int blk = t >> 6, l = t & 63;
    int ks = blk & 1, hf = blk >> 1;
    int h  = hf * 16 + (l & 15);
    int k0 = ks * 32 + (l >> 4) * 8;
#pragma unroll
    for (int j = 0; j < 8; ++j) v[j] = (__bf16)W1[(k0 + j) * 256 + h];
    *(bf16x8*)(ws + t * 16) = v;
  } else if (t < 10240) {             // GEMM2: 128 blocks * 64 lanes
    int t2 = t - 2048;
    int blk = t2 >> 6, l = t2 & 63;
    int ks = blk & 1;
    int c  = (blk >> 1) & 3;
    int of = blk >> 3;
    int o  = of * 16 + (l & 15);
    int f0 = c * 64 + ks * 32 + (l >> 4) * 8;
#pragma unroll
    for (int j = 0; j < 8; ++j) v[j] = (__bf16)W2[(f0 + j) * 256 + o];
    *(bf16x8*)(ws + 32768 + t2 * 16) = v;
  }
}

// ---------------------------------------------------------------------------
// main fused kernel: 256 threads = 4 waves; block = 2 graphs = 48 rows.
// wave ow = wid: o-tile ow*64 (4 fi); each wave covers all 48 rows (3 fj).
// ldsX and ldsH are separate regions -> no union-protect barrier needed.
// ---------------------------------------------------------------------------
__launch_bounds__(256, 4)
__global__ void gnn_kernel(const float* __restrict__ X,
                           const float* __restrict__ b1g,
                           const float* __restrict__ b2g,
                           const float* __restrict__ Ag,
                           const unsigned char* __restrict__ ws,
                           float* __restrict__ out) {
  __shared__ __align__(16) unsigned char ldsX[48 * 128];   // X' bf16 swz 6K
  __shared__ __align__(16) unsigned char ldsH[48 * 512];   // H1 bf16 swz 24K
  __shared__ __align__(16) float ldsB1[256];
  __shared__ __align__(16) float ldsB2[256];
  __shared__ __align__(16) float wdT[24];   // A[n][n-1], 0 at n=0
  __shared__ __align__(16) float w0T[24];   // A[n][n]
  __shared__ __align__(16) float wuT[24];   // A[n][n+1], 0 at n=23

  const int tid  = threadIdx.x;
  const int lane = tid & 63;
  const int ow   = tid >> 6;           // wave id = o-tile
  const int g0   = blockIdx.x * 2;
  const long row0 = (long)g0 * 24;

  const int r16   = lane & 15;
  const int kgrp  = (lane >> 4) * 8;
  const int lbyte = lane * 16;

  // ---- GEMM1 weight fragments issued FIRST: latency hides under staging
  bf16x8 af1[2][4];
#pragma unroll
  for (int ks = 0; ks < 2; ++ks)
#pragma unroll
    for (int fi = 0; fi < 4; ++fi)
      af1[ks][fi] = *(const bf16x8*)(ws + ((((ow * 4 + fi) * 2) + ks) << 10) + lbyte);

  ldsB1[tid] = b1g[tid];
  ldsB2[tid] = b2g[tid];
  if (tid < 24) {
    wdT[tid] = tid > 0  ? Ag[tid * 25 - 1] : 0.f;
    w0T[tid] = Ag[tid * 25];
    wuT[tid] = tid < 23 ? Ag[tid * 25 + 1] : 0.f;
  }

  // ---- X' = (A @ X) rows (tridiagonal mix) -> bf16 swizzled into ldsX
  // Unconditional clamped loads: no divergent branches, loads batchable.
#pragma unroll
  for (int it = 0; it < 3; ++it) {
    int idx = tid + it * 256;            // 48 rows x 16 float4-chunks
    int m   = idx >> 4;
    int c4  = (idx & 15) * 4;
    int n   = m - (m / 24) * 24;
    int md  = (n > 0)  ? m - 1 : m;      // clamped; weight 0 at chain start
    int mu  = (n < 23) ? m + 1 : m;      // clamped; weight 0 at chain end
    int od  = (n > 0)  ? n * 25 - 1 : 0;
    int ou  = (n < 23) ? n * 25 + 1 : 0;
    float wmid = Ag[n * 25];
    float wdn  = Ag[od];  wdn = (n > 0)  ? wdn : 0.f;
    float wup  = Ag[ou];  wup = (n < 23) ? wup : 0.f;
    float4 xc = *(const float4*)(X + (row0 + m)  * 64 + c4);
    float4 xd = *(const float4*)(X + (row0 + md) * 64 + c4);
    float4 xu = *(const float4*)(X + (row0 + mu) * 64 + c4);
    float ax = wmid * xc.x + wdn * xd.x + wup * xu.x;
    float ay = wmid * xc.y + wdn * xd.y + wup * xu.y;
    float az = wmid * xc.z + wdn * xd.z + wup * xu.z;
    float aw = wmid * xc.w + wdn * xd.w + wup * xu.w;
    bf16x4 p;
    p[0] = (__bf16)ax; p[1] = (__bf16)ay; p[2] = (__bf16)az; p[3] = (__bf16)aw;
    *(bf16x4*)(ldsX + SWZ(m, m * 128 + c4 * 2)) = p;
  }
  __syncthreads();   // barrA: X' + biases + coeff tables ready

  f32x4 acc[4][3];
  const f32x4 z4 = {0.f, 0.f, 0.f, 0.f};
#pragma unroll
  for (int i = 0; i < 4; ++i)
#pragma unroll
    for (int j = 0; j < 3; ++j) acc[i][j] = z4;

  // ---- GEMM1: D[h][m] = W1T(h,k) * X'(m,k)^T, K=64 (weights in registers)
#pragma unroll
  for (int ks = 0; ks < 2; ++ks) {
    bf16x8 bf[3];
    int koff = (ks * 32 + kgrp) * 2;
#pragma unroll
    for (int fj = 0; fj < 3; ++fj) {
      int m = fj * 16 + r16;
      bf[fj] = *(const bf16x8*)(ldsX + SWZ(m, m * 128 + koff));
    }
#pragma unroll
    for (int fi = 0; fi < 4; ++fi)
#pragma unroll
      for (int fj = 0; fj < 3; ++fj)
        acc[fi][fj] = __builtin_amdgcn_mfma_f32_16x16x32_bf16(af1[ks][fi], bf[fj], acc[fi][fj], 0, 0, 0);
  }
  // no barrier here: ldsX and ldsH are separate regions

  // ---- epilogue1: bias + ReLU -> H1[m][h] bf16 (D: col=lane&15=m, row=(lane>>4)*4+reg=h)
  {
    int hr = (lane >> 4) * 4;
#pragma unroll
    for (int fi = 0; fi < 4; ++fi) {
      int h = ow * 64 + fi * 16 + hr;
      float4 bb = *(const float4*)&ldsB1[h];
#pragma unroll
      for (int fj = 0; fj < 3; ++fj) {
        int m = fj * 16 + r16;
        f32x4 v = acc[fi][fj];
        bf16x4 p;
        p[0] = (__bf16)fmaxf(v[0] + bb.x, 0.f);
        p[1] = (__bf16)fmaxf(v[1] + bb.y, 0.f);
        p[2] = (__bf16)fmaxf(v[2] + bb.z, 0.f);
        p[3] = (__bf16)fmaxf(v[3] + bb.w, 0.f);
        *(bf16x4*)(ldsH + SWZ(m, m * 512 + h * 2)) = p;
      }
    }
  }
  __syncthreads();   // barrC: H1 ready

  // ---- GEMM2 (operands swapped): D[m][o] = H1(m,f) * W2T(o,f)^T, K=256.
  // 2-step-deep rotating prefetch: afA = step s, afB = s+1, afC <- s+2.
  // lane holds m = fj*16 + (lane>>4)*4 + r (4 consecutive rows),
  // o = ow*64 + fi*16 + (lane&15).
  f32x4 acc2[3][4];
#pragma unroll
  for (int j = 0; j < 3; ++j)
#pragma unroll
    for (int i = 0; i < 4; ++i) acc2[j][i] = z4;

  const unsigned char* w2p = ws + 32768;
#define W2ADDR(s, fi) ((const bf16x8*)(w2p + \
    ((((ow * 4 + (fi)) * 4 + ((s) >> 1)) * 2 + ((s) & 1)) << 10) + lbyte))

  bf16x8 afA[4], afB[4];
#pragma unroll
  for (int fi = 0; fi < 4; ++fi) afA[fi] = *W2ADDR(0, fi);
#pragma unroll
  for (int fi = 0; fi < 4; ++fi) afB[fi] = *W2ADDR(1, fi);

#pragma unroll
  for (int s = 0; s < 8; ++s) {
    bf16x8 afC[4];
    if (s < 6) {
#pragma unroll
      for (int fi = 0; fi < 4; ++fi) afC[fi] = *W2ADDR(s + 2, fi);
    }
    const int c  = s >> 1;
    const int ks = s & 1;
    bf16x8 bf[3];
    int foff = (c * 64 + ks * 32 + kgrp) * 2;
#pragma unroll
    for (int fj = 0; fj < 3; ++fj) {
      int m = fj * 16 + r16;
      bf[fj] = *(const bf16x8*)(ldsH + SWZ(m, m * 512 + foff));
    }
#pragma unroll
    for (int fj = 0; fj < 3; ++fj)
#pragma unroll
      for (int fi = 0; fi < 4; ++fi)
        acc2[fj][fi] = __builtin_amdgcn_mfma_f32_16x16x32_bf16(bf[fj], afA[fi], acc2[fj][fi], 0, 0, 0);
#pragma unroll
    for (int fi = 0; fi < 4; ++fi) { afA[fi] = afB[fi]; afB[fi] = afC[fi]; }
  }
#undef W2ADDR
  // no barrier needed: everything below is in-register

  // ---- final: in-register tri-mix + bias + ReLU + mean-pool over 24 nodes.
  // acc2[fj][fi][r] = Z[m][o], m lm = fj*16 + grp*4 + r (grp = lane>>4),
  // graph = (lm >= 24), n = lm % 24. Edge weights wdT[0] = wuT[23] = 0 kill
  // cross-graph garbage automatically.
  {
    const int grp = lane >> 4;
    const int l16 = lane & 15;
    const int src_up = (lane - 16) & 63;   // receive value of lane-16
    const int src_dn = (lane + 16) & 63;   // receive value of lane+16

    // batch ALL cross-lane moves first: 24 DS ops, latencies overlap
    float s3[4][3], s0[4][3];
#pragma unroll
    for (int fi = 0; fi < 4; ++fi)
#pragma unroll
      for (int fj = 0; fj < 3; ++fj) {
        s3[fi][fj] = __shfl(acc2[fj][fi][3], src_up);  // Z[lm-1] cand for r=0
        s0[fi][fj] = __shfl(acc2[fj][fi][0], src_dn);  // Z[lm+1] cand for r=3
      }

#pragma unroll
    for (int fi = 0; fi < 4; ++fi) {
      const int o = ow * 64 + fi * 16 + l16;
      const float b2v = ldsB2[o];
      float p0 = 0.f, p1 = 0.f;
#pragma unroll
      for (int fj = 0; fj < 3; ++fj) {
        const int lmb = fj * 16 + grp * 4;
        const int nb  = (lmb < 24) ? lmb : lmb - 24;
        f32x4 wd4 = *(const f32x4*)&wdT[nb];
        f32x4 w04 = *(const f32x4*)&w0T[nb];
        f32x4 wu4 = *(const f32x4*)&wuT[nb];
        f32x4 v = acc2[fj][fi];
        float zl0 = s3[fi][fj], zr3 = s0[fi][fj];
        if (fj > 0 && grp == 0) zl0 = s3[fi][fj - 1];  // cross-frag left nbr
        if (fj < 2 && grp == 3) zr3 = s0[fi][fj + 1];  // cross-frag right nbr
        float q0 = b2v + wd4[0] * zl0 + w04[0] * v[0] + wu4[0] * v[1];
        float q1 = b2v + wd4[1] * v[0] + w04[1] * v[1] + wu4[1] * v[2];
        float q2 = b2v + wd4[2] * v[1] + w04[2] * v[2] + wu4[2] * v[3];
        float q3 = b2v + wd4[3] * v[2] + w04[3] * v[3] + wu4[3] * zr3;
        float qs = fmaxf(q0, 0.f) + fmaxf(q1, 0.f) +
                   fmaxf(q2, 0.f) + fmaxf(q3, 0.f);
        if (fj == 0) p0 += qs;
        else if (fj == 2) p1 += qs;
        else { bool low = grp < 2; p0 += low ? qs : 0.f; p1 += low ? 0.f : qs; }
      }
      // pool across the 4 row-groups (same l16 = same o)
      p0 += __shfl_xor(p0, 16); p0 += __shfl_xor(p0, 32);
      p1 += __shfl_xor(p1, 16); p1 += __shfl_xor(p1, 32);
      if (grp == 0) out[(size_t)(g0)     * 256 + o] = p0 * (1.f / 24.f);
      if (grp == 1) out[(size_t)(g0 + 1) * 256 + o] = p1 * (1.f / 24.f);
    }
  }
}

extern "C" void kernel_launch(void* const* d_in, const int* in_sizes, int n_in,
                              void* d_out, int out_size, void* d_ws, size_t ws_size,
                              hipStream_t stream) {
  (void)n_in; (void)out_size; (void)ws_size;
  const float* X  = (const float*)d_in[0];
  const float* W1 = (const float*)d_in[1];
  const float* b1 = (const float*)d_in[2];
  const float* W2 = (const float*)d_in[3];
  const float* b2 = (const float*)d_in[4];
  const float* A  = (const float*)d_in[5];
  float* out = (float*)d_out;
  unsigned char* ws = (unsigned char*)d_ws;

  int B = in_sizes[0] / (24 * 64);   // 8192
  prep_kernel<<<40, 256, 0, stream>>>(W1, W2, ws);
  gnn_kernel<<<B / 2, 256, 0, stream>>>(X, b1, b2, A, ws, out);
}

// Round 26
// 53.400 us; speedup vs baseline: 1.0372x; 1.0043x over previous
//
#include <hip/hip_runtime.h>
#include <stdint.h>

// JointGNNEncoder fused 2-layer GCN, MI355X (gfx950).
// out[b] = mean_n ReLU( A @ ( ReLU( A @ (X W1) + b1 ) W2 ) + b2 )
// A@(X W) = (A@X) W ; A is tridiagonal (chains are index-contiguous).
// R26 = R25 (53.6us) + GEMM2's first two weight-fragment sets (afA/afB,
// 32 VGPR) issued BEFORE epilogue1: L2 latency hides under epilogue VALU +
// ds_writes + barrC wait. Last uncovered load-head in the kernel.
// Live range crosses an epilogue+barrier, NOT a GEMM (spill-safe class).

typedef __attribute__((ext_vector_type(8))) __bf16 bf16x8;
typedef __attribute__((ext_vector_type(4))) __bf16 bf16x4;
typedef __attribute__((ext_vector_type(4))) float f32x4;

// XOR bits 4..6 by row&7: spreads 16B slots of same-bank rows across banks
#define SWZ(row, byteoff) ((unsigned)(byteoff) ^ ((((unsigned)(row)) & 7u) << 4))

// ---------------------------------------------------------------------------
// prep: pack bf16 weights in per-fragment lane order.
// GEMM1 frag block idx = (hf*2 + ks): lane l holds
//   W1T(h = hf*16 + (l&15), k = ks*32 + (l>>4)*8 + j), j=0..7  -> ws[0,32K)
// GEMM2 frag block idx = ((of*4 + c)*2 + ks): lane l holds
//   W2T(o = of*16 + (l&15), f = c*64 + ks*32 + (l>>4)*8 + j)   -> ws[32K,160K)
// ---------------------------------------------------------------------------
__global__ void prep_kernel(const float* __restrict__ W1,
                            const float* __restrict__ W2,
                            unsigned char* __restrict__ ws) {
  int t = blockIdx.x * blockDim.x + threadIdx.x;
  bf16x8 v;
  if (t < 2048) {                     // GEMM1: 32 blocks * 64 lanes
    int blk = t >> 6, l = t & 63;
    int ks = blk & 1, hf = blk >> 1;
    int h  = hf * 16 + (l & 15);
    int k0 = ks * 32 + (l >> 4) * 8;
#pragma unroll
    for (int j = 0; j < 8; ++j) v[j] = (__bf16)W1[(k0 + j) * 256 + h];
    *(bf16x8*)(ws + t * 16) = v;
  } else if (t < 10240) {             // GEMM2: 128 blocks * 64 lanes
    int t2 = t - 2048;
    int blk = t2 >> 6, l = t2 & 63;
    int ks = blk & 1;
    int c  = (blk >> 1) & 3;
    int of = blk >> 3;
    int o  = of * 16 + (l & 15);
    int f0 = c * 64 + ks * 32 + (l >> 4) * 8;
#pragma unroll
    for (int j = 0; j < 8; ++j) v[j] = (__bf16)W2[(f0 + j) * 256 + o];
    *(bf16x8*)(ws + 32768 + t2 * 16) = v;
  }
}

// ---------------------------------------------------------------------------
// main fused kernel: 256 threads = 4 waves; block = 2 graphs = 48 rows.
// wave ow = wid: o-tile ow*64 (4 fi); each wave covers all 48 rows (3 fj).
// ldsX and ldsH are separate regions -> no union-protect barrier needed.
// ---------------------------------------------------------------------------
__launch_bounds__(256, 4)
__global__ void gnn_kernel(const float* __restrict__ X,
                           const float* __restrict__ b1g,
                           const float* __restrict__ b2g,
                           const float* __restrict__ Ag,
                           const unsigned char* __restrict__ ws,
                           float* __restrict__ out) {
  __shared__ __align__(16) unsigned char ldsX[48 * 128];   // X' bf16 swz 6K
  __shared__ __align__(16) unsigned char ldsH[48 * 512];   // H1 bf16 swz 24K
  __shared__ __align__(16) float ldsB1[256];
  __shared__ __align__(16) float ldsB2[256];
  __shared__ __align__(16) float wdT[24];   // A[n][n-1], 0 at n=0
  __shared__ __align__(16) float w0T[24];   // A[n][n]
  __shared__ __align__(16) float wuT[24];   // A[n][n+1], 0 at n=23

  const int tid  = threadIdx.x;
  const int lane = tid & 63;
  const int ow   = tid >> 6;           // wave id = o-tile
  const int g0   = blockIdx.x * 2;
  const long row0 = (long)g0 * 24;

  const int r16   = lane & 15;
  const int kgrp  = (lane >> 4) * 8;
  const int lbyte = lane * 16;
  const unsigned char* w2p = ws + 32768;
#define W2ADDR(s, fi) ((const bf16x8*)(w2p + \
    ((((ow * 4 + (fi)) * 4 + ((s) >> 1)) * 2 + ((s) & 1)) << 10) + lbyte))

  // ---- GEMM1 weight fragments issued FIRST: latency hides under staging
  bf16x8 af1[2][4];
#pragma unroll
  for (int ks = 0; ks < 2; ++ks)
#pragma unroll
    for (int fi = 0; fi < 4; ++fi)
      af1[ks][fi] = *(const bf16x8*)(ws + ((((ow * 4 + fi) * 2) + ks) << 10) + lbyte);

  ldsB1[tid] = b1g[tid];
  ldsB2[tid] = b2g[tid];
  if (tid < 24) {
    wdT[tid] = tid > 0  ? Ag[tid * 25 - 1] : 0.f;
    w0T[tid] = Ag[tid * 25];
    wuT[tid] = tid < 23 ? Ag[tid * 25 + 1] : 0.f;
  }

  // ---- X' = (A @ X) rows (tridiagonal mix) -> bf16 swizzled into ldsX
  // Unconditional clamped loads: no divergent branches, loads batchable.
#pragma unroll
  for (int it = 0; it < 3; ++it) {
    int idx = tid + it * 256;            // 48 rows x 16 float4-chunks
    int m   = idx >> 4;
    int c4  = (idx & 15) * 4;
    int n   = m - (m / 24) * 24;
    int md  = (n > 0)  ? m - 1 : m;      // clamped; weight 0 at chain start
    int mu  = (n < 23) ? m + 1 : m;      // clamped; weight 0 at chain end
    int od  = (n > 0)  ? n * 25 - 1 : 0;
    int ou  = (n < 23) ? n * 25 + 1 : 0;
    float wmid = Ag[n * 25];
    float wdn  = Ag[od];  wdn = (n > 0)  ? wdn : 0.f;
    float wup  = Ag[ou];  wup = (n < 23) ? wup : 0.f;
    float4 xc = *(const float4*)(X + (row0 + m)  * 64 + c4);
    float4 xd = *(const float4*)(X + (row0 + md) * 64 + c4);
    float4 xu = *(const float4*)(X + (row0 + mu) * 64 + c4);
    float ax = wmid * xc.x + wdn * xd.x + wup * xu.x;
    float ay = wmid * xc.y + wdn * xd.y + wup * xu.y;
    float az = wmid * xc.z + wdn * xd.z + wup * xu.z;
    float aw = wmid * xc.w + wdn * xd.w + wup * xu.w;
    bf16x4 p;
    p[0] = (__bf16)ax; p[1] = (__bf16)ay; p[2] = (__bf16)az; p[3] = (__bf16)aw;
    *(bf16x4*)(ldsX + SWZ(m, m * 128 + c4 * 2)) = p;
  }
  __syncthreads();   // barrA: X' + biases + coeff tables ready

  f32x4 acc[4][3];
  const f32x4 z4 = {0.f, 0.f, 0.f, 0.f};
#pragma unroll
  for (int i = 0; i < 4; ++i)
#pragma unroll
    for (int j = 0; j < 3; ++j) acc[i][j] = z4;

  // ---- GEMM1: D[h][m] = W1T(h,k) * X'(m,k)^T, K=64 (weights in registers)
#pragma unroll
  for (int ks = 0; ks < 2; ++ks) {
    bf16x8 bf[3];
    int koff = (ks * 32 + kgrp) * 2;
#pragma unroll
    for (int fj = 0; fj < 3; ++fj) {
      int m = fj * 16 + r16;
      bf[fj] = *(const bf16x8*)(ldsX + SWZ(m, m * 128 + koff));
    }
#pragma unroll
    for (int fi = 0; fi < 4; ++fi)
#pragma unroll
      for (int fj = 0; fj < 3; ++fj)
        acc[fi][fj] = __builtin_amdgcn_mfma_f32_16x16x32_bf16(af1[ks][fi], bf[fj], acc[fi][fj], 0, 0, 0);
  }
  // no barrier here: ldsX and ldsH are separate regions

  // ---- issue GEMM2's first two weight sets NOW: L2 latency hides under
  // epilogue1 (VALU + ds_writes) and the barrC wait. Depends only on ow/lbyte.
  bf16x8 afA[4], afB[4];
#pragma unroll
  for (int fi = 0; fi < 4; ++fi) afA[fi] = *W2ADDR(0, fi);
#pragma unroll
  for (int fi = 0; fi < 4; ++fi) afB[fi] = *W2ADDR(1, fi);

  // ---- epilogue1: bias + ReLU -> H1[m][h] bf16 (D: col=lane&15=m, row=(lane>>4)*4+reg=h)
  {
    int hr = (lane >> 4) * 4;
#pragma unroll
    for (int fi = 0; fi < 4; ++fi) {
      int h = ow * 64 + fi * 16 + hr;
      float4 bb = *(const float4*)&ldsB1[h];
#pragma unroll
      for (int fj = 0; fj < 3; ++fj) {
        int m = fj * 16 + r16;
        f32x4 v = acc[fi][fj];
        bf16x4 p;
        p[0] = (__bf16)fmaxf(v[0] + bb.x, 0.f);
        p[1] = (__bf16)fmaxf(v[1] + bb.y, 0.f);
        p[2] = (__bf16)fmaxf(v[2] + bb.z, 0.f);
        p[3] = (__bf16)fmaxf(v[3] + bb.w, 0.f);
        *(bf16x4*)(ldsH + SWZ(m, m * 512 + h * 2)) = p;
      }
    }
  }
  __syncthreads();   // barrC: H1 ready

  // ---- GEMM2 (operands swapped): D[m][o] = H1(m,f) * W2T(o,f)^T, K=256.
  // 2-step-deep rotating prefetch: afA = step s, afB = s+1, afC <- s+2.
  // lane holds m = fj*16 + (lane>>4)*4 + r (4 consecutive rows),
  // o = ow*64 + fi*16 + (lane&15).
  f32x4 acc2[3][4];
#pragma unroll
  for (int j = 0; j < 3; ++j)
#pragma unroll
    for (int i = 0; i < 4; ++i) acc2[j][i] = z4;

#pragma unroll
  for (int s = 0; s < 8; ++s) {
    bf16x8 afC[4];
    if (s < 6) {
#pragma unroll
      for (int fi = 0; fi < 4; ++fi) afC[fi] = *W2ADDR(s + 2, fi);
    }
    const int c  = s >> 1;
    const int ks = s & 1;
    bf16x8 bf[3];
    int foff = (c * 64 + ks * 32 + kgrp) * 2;
#pragma unroll
    for (int fj = 0; fj < 3; ++fj) {
      int m = fj * 16 + r16;
      bf[fj] = *(const bf16x8*)(ldsH + SWZ(m, m * 512 + foff));
    }
#pragma unroll
    for (int fj = 0; fj < 3; ++fj)
#pragma unroll
      for (int fi = 0; fi < 4; ++fi)
        acc2[fj][fi] = __builtin_amdgcn_mfma_f32_16x16x32_bf16(bf[fj], afA[fi], acc2[fj][fi], 0, 0, 0);
#pragma unroll
    for (int fi = 0; fi < 4; ++fi) { afA[fi] = afB[fi]; afB[fi] = afC[fi]; }
  }
#undef W2ADDR
  // no barrier needed: everything below is in-register

  // ---- final: in-register tri-mix + bias + ReLU + mean-pool over 24 nodes.
  // acc2[fj][fi][r] = Z[m][o], m lm = fj*16 + grp*4 + r (grp = lane>>4),
  // graph = (lm >= 24), n = lm % 24. Edge weights wdT[0] = wuT[23] = 0 kill
  // cross-graph garbage automatically.
  {
    const int grp = lane >> 4;
    const int l16 = lane & 15;
    const int src_up = (lane - 16) & 63;   // receive value of lane-16
    const int src_dn = (lane + 16) & 63;   // receive value of lane+16

    // batch ALL cross-lane moves first: 24 DS ops, latencies overlap
    float s3[4][3], s0[4][3];
#pragma unroll
    for (int fi = 0; fi < 4; ++fi)
#pragma unroll
      for (int fj = 0; fj < 3; ++fj) {
        s3[fi][fj] = __shfl(acc2[fj][fi][3], src_up);  // Z[lm-1] cand for r=0
        s0[fi][fj] = __shfl(acc2[fj][fi][0], src_dn);  // Z[lm+1] cand for r=3
      }

#pragma unroll
    for (int fi = 0; fi < 4; ++fi) {
      const int o = ow * 64 + fi * 16 + l16;
      const float b2v = ldsB2[o];
      float p0 = 0.f, p1 = 0.f;
#pragma unroll
      for (int fj = 0; fj < 3; ++fj) {
        const int lmb = fj * 16 + grp * 4;
        const int nb  = (lmb < 24) ? lmb : lmb - 24;
        f32x4 wd4 = *(const f32x4*)&wdT[nb];
        f32x4 w04 = *(const f32x4*)&w0T[nb];
        f32x4 wu4 = *(const f32x4*)&wuT[nb];
        f32x4 v = acc2[fj][fi];
        float zl0 = s3[fi][fj], zr3 = s0[fi][fj];
        if (fj > 0 && grp == 0) zl0 = s3[fi][fj - 1];  // cross-frag left nbr
        if (fj < 2 && grp == 3) zr3 = s0[fi][fj + 1];  // cross-frag right nbr
        float q0 = b2v + wd4[0] * zl0 + w04[0] * v[0] + wu4[0] * v[1];
        float q1 = b2v + wd4[1] * v[0] + w04[1] * v[1] + wu4[1] * v[2];
        float q2 = b2v + wd4[2] * v[1] + w04[2] * v[2] + wu4[2] * v[3];
        float q3 = b2v + wd4[3] * v[2] + w04[3] * v[3] + wu4[3] * zr3;
        float qs = fmaxf(q0, 0.f) + fmaxf(q1, 0.f) +
                   fmaxf(q2, 0.f) + fmaxf(q3, 0.f);
        if (fj == 0) p0 += qs;
        else if (fj == 2) p1 += qs;
        else { bool low = grp < 2; p0 += low ? qs : 0.f; p1 += low ? 0.f : qs; }
      }
      // pool across the 4 row-groups (same l16 = same o)
      p0 += __shfl_xor(p0, 16); p0 += __shfl_xor(p0, 32);
      p1 += __shfl_xor(p1, 16); p1 += __shfl_xor(p1, 32);
      if (grp == 0) out[(size_t)(g0)     * 256 + o] = p0 * (1.f / 24.f);
      if (grp == 1) out[(size_t)(g0 + 1) * 256 + o] = p1 * (1.f / 24.f);
    }
  }
}

extern "C" void kernel_launch(void* const* d_in, const int* in_sizes, int n_in,
                              void* d_out, int out_size, void* d_ws, size_t ws_size,
                              hipStream_t stream) {
  (void)n_in; (void)out_size; (void)ws_size;
  const float* X  = (const float*)d_in[0];
  const float* W1 = (const float*)d_in[1];
  const float* b1 = (const float*)d_in[2];
  const float* W2 = (const float*)d_in[3];
  const float* b2 = (const float*)d_in[4];
  const float* A  = (const float*)d_in[5];
  float* out = (float*)d_out;
  unsigned char* ws = (unsigned char*)d_ws;

  int B = in_sizes[0] / (24 * 64);   // 8192
  prep_kernel<<<40, 256, 0, stream>>>(W1, W2, ws);
  gnn_kernel<<<B / 2, 256, 0, stream>>>(X, b1, b2, A, ws, out);
}